// Round 1
// baseline (441.404 us; speedup 1.0000x reference)
//
#include <hip/hip_runtime.h>
#include <math.h>

// Problem constants (reference: B=4, T=2048, C=1024, H=16, d=64)
#define BB   4
#define TT   2048
#define CC   1024
#define HH   16
#define DD   64
#define MM   (BB*TT)     // 8192 rows
#define NQKV (3*CC)      // 3072
#define LCH  128         // attention chunk length
#define NCH  (TT/LCH)    // 16 chunks per (b,h)
#define EPSF 1e-6f

typedef __bf16 bf16x8 __attribute__((ext_vector_type(8)));
typedef float  floatx4 __attribute__((ext_vector_type(4)));

__device__ __forceinline__ unsigned short f2bf(float f) {
  union { float f; unsigned int u; } v; v.f = f;
  unsigned int r = v.u + 0x7fffu + ((v.u >> 16) & 1u); // RNE
  return (unsigned short)(r >> 16);
}
__device__ __forceinline__ float bf2f(unsigned short s) {
  union { unsigned int u; float f; } v; v.u = ((unsigned int)s) << 16;
  return v.f;
}
__device__ __forceinline__ float2 bf2x2(unsigned int w) {
  union { unsigned int u; float f; } lo, hi;
  lo.u = w << 16; hi.u = w & 0xffff0000u;
  float2 r; r.x = lo.f; r.y = hi.f; return r;
}
__device__ __forceinline__ float featmap(float v) {
  // elu(v)+1
  return v > 0.f ? v + 1.f : __expf(v);
}

// ---------------- conversion kernels ----------------

__global__ __launch_bounds__(256) void cvt_x_kernel(const float* __restrict__ x,
                                                    unsigned short* __restrict__ xb, int n) {
  int i = (blockIdx.x * 256 + threadIdx.x) * 4;
  if (i < n) {
    float4 f = *(const float4*)(x + i);
    ushort4 o;
    o.x = f2bf(f.x); o.y = f2bf(f.y); o.z = f2bf(f.z); o.w = f2bf(f.w);
    *(ushort4*)(xb + i) = o;
  }
}

// W: R x Cc fp32 row-major  ->  out: Cc x R bf16 row-major (transposed)
__global__ __launch_bounds__(256) void transpose_cvt_kernel(const float* __restrict__ W,
                                                            unsigned short* __restrict__ out,
                                                            int R, int Cc) {
  __shared__ float tile[32][33];
  int bx = blockIdx.x * 32;   // source col base
  int by = blockIdx.y * 32;   // source row base
  int tx = threadIdx.x, ty = threadIdx.y;  // 32 x 8
  #pragma unroll
  for (int i = ty; i < 32; i += 8)
    tile[i][tx] = W[(size_t)(by + i) * Cc + bx + tx];
  __syncthreads();
  #pragma unroll
  for (int i = ty; i < 32; i += 8)
    out[(size_t)(bx + i) * R + by + tx] = f2bf(tile[tx][i]);
}

// ---------------- GEMM 1: qkv = x @ W_attn + b, split + feature map ----------------
// A:  M x K   bf16 row-major (xb)
// Bt: N x K   bf16 row-major (W_attn transposed)
// grid (N/128, M/128), 256 threads (4 waves, each wave a 64x64 quadrant)
__global__ __launch_bounds__(256) void gemm_qkv_kernel(
    const unsigned short* __restrict__ A, const unsigned short* __restrict__ Bt,
    const float* __restrict__ bias,
    unsigned short* __restrict__ qh, unsigned short* __restrict__ kh,
    unsigned short* __restrict__ vh) {
  const int K = CC;
  __shared__ __align__(16) unsigned short As[128 * 32];
  __shared__ __align__(16) unsigned short Bs[128 * 32];
  int tid = threadIdx.x;
  int wave = tid >> 6, lane = tid & 63;
  int lr = lane & 15, lq = lane >> 4;
  int m0 = blockIdx.y * 128, n0 = blockIdx.x * 128;
  int wm = (wave >> 1) * 64, wn = (wave & 1) * 64;
  floatx4 acc[4][4] = {};
  for (int k0 = 0; k0 < K; k0 += 32) {
    #pragma unroll
    for (int s = tid; s < 512; s += 256) {
      int row = s >> 2, k8 = (s & 3) << 3;
      *(uint4*)&As[row * 32 + k8] = *(const uint4*)&A[(size_t)(m0 + row) * K + k0 + k8];
      *(uint4*)&Bs[row * 32 + k8] = *(const uint4*)&Bt[(size_t)(n0 + row) * K + k0 + k8];
    }
    __syncthreads();
    bf16x8 af[4], bfr[4];
    #pragma unroll
    for (int i = 0; i < 4; i++) af[i] = *(const bf16x8*)&As[(wm + i * 16 + lr) * 32 + lq * 8];
    #pragma unroll
    for (int j = 0; j < 4; j++) bfr[j] = *(const bf16x8*)&Bs[(wn + j * 16 + lr) * 32 + lq * 8];
    #pragma unroll
    for (int i = 0; i < 4; i++)
      #pragma unroll
      for (int j = 0; j < 4; j++)
        acc[i][j] = __builtin_amdgcn_mfma_f32_16x16x32_bf16(af[i], bfr[j], acc[i][j], 0, 0, 0);
    __syncthreads();
  }
  // epilogue: C/D layout col=lane&15, row=(lane>>4)*4+reg
  #pragma unroll
  for (int i = 0; i < 4; i++) {
    #pragma unroll
    for (int j = 0; j < 4; j++) {
      #pragma unroll
      for (int r = 0; r < 4; r++) {
        int row = wm + i * 16 + lq * 4 + r;
        int col = wn + j * 16 + lr;
        int m = m0 + row, n = n0 + col;
        float v = acc[i][j][r] + bias[n];
        int which = n >> 10, c = n & 1023;
        int h = c >> 6, dd = c & 63;
        int b = m >> 11, t = m & 2047;
        size_t idx = (((size_t)(b * HH + h)) * TT + t) * DD + dd;
        if (which == 0)      qh[idx] = f2bf(featmap(v));
        else if (which == 1) kh[idx] = f2bf(featmap(v));
        else                 vh[idx] = f2bf(v);
      }
    }
  }
}

// ---------------- Phase A: per-chunk KV state ----------------
// grid: B*H*NCH blocks, 256 threads. KV[blk] = K_c^T V_c (d x d fp32), Ksum[blk]
__global__ __launch_bounds__(256) void chunk_state_kernel(
    const unsigned short* __restrict__ kh, const unsigned short* __restrict__ vh,
    float* __restrict__ KV, float* __restrict__ Ksum) {
  int blk = blockIdx.x;
  int bh = blk / NCH, c = blk % NCH;
  const unsigned short* kp = kh + ((size_t)bh * TT + c * LCH) * DD;
  const unsigned short* vp = vh + ((size_t)bh * TT + c * LCH) * DD;
  __shared__ float ks[LCH * DD];  // 32 KB
  __shared__ float vs[LCH * DD];  // 32 KB
  for (int e = threadIdx.x; e < LCH * DD; e += 256) {
    ks[e] = bf2f(kp[e]);
    vs[e] = bf2f(vp[e]);
  }
  __syncthreads();
  int j = threadIdx.x & 63, i0 = (threadIdx.x >> 6) * 16;
  float acc[16];
  #pragma unroll
  for (int ii = 0; ii < 16; ii++) acc[ii] = 0.f;
  for (int t = 0; t < LCH; t++) {
    float vv = vs[t * DD + j];
    #pragma unroll
    for (int ii = 0; ii < 16; ii++) acc[ii] += ks[t * DD + i0 + ii] * vv;
  }
  float* kvout = KV + (size_t)blk * DD * DD;
  #pragma unroll
  for (int ii = 0; ii < 16; ii++) kvout[(i0 + ii) * DD + j] = acc[ii];
  if (threadIdx.x < DD) {
    int i = threadIdx.x;
    float s = 0.f;
    for (int t = 0; t < LCH; t++) s += ks[t * DD + i];
    Ksum[(size_t)blk * DD + i] = s;
  }
}

// ---------------- Phase B: exclusive prefix over chunks (in place) ----------------
// grid: B*H blocks, 256 threads
__global__ __launch_bounds__(256) void prefix_state_kernel(float* __restrict__ KV,
                                                           float* __restrict__ Ksum) {
  int bh = blockIdx.x;
  int e0 = threadIdx.x * 16;
  float run[16];
  #pragma unroll
  for (int ii = 0; ii < 16; ii++) run[ii] = 0.f;
  float krun = 0.f;
  int kidx = threadIdx.x;
  for (int c = 0; c < NCH; c++) {
    float* p = KV + ((size_t)bh * NCH + c) * DD * DD + e0;
    #pragma unroll
    for (int ii = 0; ii < 16; ii++) {
      float t = p[ii]; p[ii] = run[ii]; run[ii] += t;
    }
    if (kidx < DD) {
      float* kp = Ksum + ((size_t)bh * NCH + c) * DD + kidx;
      float t = *kp; *kp = krun; krun += t;
    }
  }
}

// ---------------- Phase C: per-chunk attention output ----------------
// grid: B*H*NCH blocks, 256 threads (2 threads per row, 32 cols each)
__global__ __launch_bounds__(256) void chunk_attn_kernel(
    const unsigned short* __restrict__ qh, const unsigned short* __restrict__ kh,
    const unsigned short* __restrict__ vh, const float* __restrict__ KV,
    const float* __restrict__ Ksum, unsigned short* __restrict__ yb) {
  int blk = blockIdx.x;
  int bh = blk / NCH, c = blk % NCH;
  int b = bh / HH, h = bh % HH;
  __shared__ __align__(16) unsigned short ks[LCH * DD];  // 16 KB bf16
  __shared__ __align__(16) unsigned short vs[LCH * DD];  // 16 KB bf16
  __shared__ __align__(16) float Ss[DD * DD];            // 16 KB fp32
  __shared__ float kps[DD];
  const unsigned short* kp = kh + ((size_t)bh * TT + c * LCH) * DD;
  const unsigned short* vp = vh + ((size_t)bh * TT + c * LCH) * DD;
  const unsigned short* qp = qh + ((size_t)bh * TT + c * LCH) * DD;
  for (int e = threadIdx.x; e < LCH * DD; e += 256) { ks[e] = kp[e]; vs[e] = vp[e]; }
  for (int e = threadIdx.x; e < DD * DD; e += 256) Ss[e] = KV[(size_t)blk * DD * DD + e];
  if (threadIdx.x < DD) kps[threadIdx.x] = Ksum[(size_t)blk * DD + threadIdx.x];
  __syncthreads();

  int t = threadIdx.x >> 1, j0 = (threadIdx.x & 1) * 32;
  // q row into registers (fully unrolled so it stays in VGPRs)
  float qf[DD];
  #pragma unroll
  for (int i8 = 0; i8 < 8; i8++) {
    uint4 w = *(const uint4*)&qp[(size_t)t * DD + i8 * 8];
    float2 f0 = bf2x2(w.x), f1 = bf2x2(w.y), f2 = bf2x2(w.z), f3 = bf2x2(w.w);
    qf[i8 * 8 + 0] = f0.x; qf[i8 * 8 + 1] = f0.y;
    qf[i8 * 8 + 2] = f1.x; qf[i8 * 8 + 3] = f1.y;
    qf[i8 * 8 + 4] = f2.x; qf[i8 * 8 + 5] = f2.y;
    qf[i8 * 8 + 6] = f3.x; qf[i8 * 8 + 7] = f3.y;
  }
  float acc[32];
  #pragma unroll
  for (int j = 0; j < 32; j++) acc[j] = 0.f;
  float den = 0.f;
  // inter-chunk: Q @ S_prefix, q . ksum_prefix
  #pragma unroll
  for (int i = 0; i < DD; i++) {
    float q = qf[i];
    den += q * kps[i];
    const float* srow = &Ss[i * DD + j0];
    #pragma unroll
    for (int j = 0; j < 32; j++) acc[j] += q * srow[j];
  }
  // intra-chunk: causal, inclusive of t'==t (matches reference update order)
  for (int tp = 0; tp <= t; tp++) {
    float s = 0.f;
    const unsigned short* krow = &ks[tp * DD];
    #pragma unroll
    for (int i8 = 0; i8 < 8; i8++) {
      uint4 w = *(const uint4*)&krow[i8 * 8];
      float2 f0 = bf2x2(w.x), f1 = bf2x2(w.y), f2 = bf2x2(w.z), f3 = bf2x2(w.w);
      s += qf[i8 * 8 + 0] * f0.x + qf[i8 * 8 + 1] * f0.y;
      s += qf[i8 * 8 + 2] * f1.x + qf[i8 * 8 + 3] * f1.y;
      s += qf[i8 * 8 + 4] * f2.x + qf[i8 * 8 + 5] * f2.y;
      s += qf[i8 * 8 + 6] * f3.x + qf[i8 * 8 + 7] * f3.y;
    }
    den += s;
    const unsigned short* vrow = &vs[tp * DD + j0];
    #pragma unroll
    for (int j8 = 0; j8 < 4; j8++) {
      uint4 w = *(const uint4*)&vrow[j8 * 8];
      float2 f0 = bf2x2(w.x), f1 = bf2x2(w.y), f2 = bf2x2(w.z), f3 = bf2x2(w.w);
      acc[j8 * 8 + 0] += s * f0.x; acc[j8 * 8 + 1] += s * f0.y;
      acc[j8 * 8 + 2] += s * f1.x; acc[j8 * 8 + 3] += s * f1.y;
      acc[j8 * 8 + 4] += s * f2.x; acc[j8 * 8 + 5] += s * f2.y;
      acc[j8 * 8 + 6] += s * f3.x; acc[j8 * 8 + 7] += s * f3.y;
    }
  }
  float inv = 1.f / (den + EPSF);
  size_t base = ((size_t)b * TT + c * LCH + t) * CC + h * DD + j0;
  #pragma unroll
  for (int j = 0; j < 32; j++) yb[base + j] = f2bf(acc[j] * inv);
}

// ---------------- GEMM 2: out = y @ W_proj + b_proj (fp32 out) ----------------
__global__ __launch_bounds__(256) void gemm_proj_kernel(
    const unsigned short* __restrict__ A, const unsigned short* __restrict__ Bt,
    const float* __restrict__ bias, float* __restrict__ out) {
  const int K = CC;
  __shared__ __align__(16) unsigned short As[128 * 32];
  __shared__ __align__(16) unsigned short Bs[128 * 32];
  int tid = threadIdx.x;
  int wave = tid >> 6, lane = tid & 63;
  int lr = lane & 15, lq = lane >> 4;
  int m0 = blockIdx.y * 128, n0 = blockIdx.x * 128;
  int wm = (wave >> 1) * 64, wn = (wave & 1) * 64;
  floatx4 acc[4][4] = {};
  for (int k0 = 0; k0 < K; k0 += 32) {
    #pragma unroll
    for (int s = tid; s < 512; s += 256) {
      int row = s >> 2, k8 = (s & 3) << 3;
      *(uint4*)&As[row * 32 + k8] = *(const uint4*)&A[(size_t)(m0 + row) * K + k0 + k8];
      *(uint4*)&Bs[row * 32 + k8] = *(const uint4*)&Bt[(size_t)(n0 + row) * K + k0 + k8];
    }
    __syncthreads();
    bf16x8 af[4], bfr[4];
    #pragma unroll
    for (int i = 0; i < 4; i++) af[i] = *(const bf16x8*)&As[(wm + i * 16 + lr) * 32 + lq * 8];
    #pragma unroll
    for (int j = 0; j < 4; j++) bfr[j] = *(const bf16x8*)&Bs[(wn + j * 16 + lr) * 32 + lq * 8];
    #pragma unroll
    for (int i = 0; i < 4; i++)
      #pragma unroll
      for (int j = 0; j < 4; j++)
        acc[i][j] = __builtin_amdgcn_mfma_f32_16x16x32_bf16(af[i], bfr[j], acc[i][j], 0, 0, 0);
    __syncthreads();
  }
  #pragma unroll
  for (int i = 0; i < 4; i++) {
    #pragma unroll
    for (int j = 0; j < 4; j++) {
      #pragma unroll
      for (int r = 0; r < 4; r++) {
        int row = wm + i * 16 + lq * 4 + r;
        int col = wn + j * 16 + lr;
        int m = m0 + row, n = n0 + col;
        out[(size_t)m * CC + n] = acc[i][j][r] + bias[n];
      }
    }
  }
}

// ---------------- host launch ----------------
extern "C" void kernel_launch(void* const* d_in, const int* in_sizes, int n_in,
                              void* d_out, int out_size, void* d_ws, size_t ws_size,
                              hipStream_t stream) {
  const float* x      = (const float*)d_in[0];
  const float* W_attn = (const float*)d_in[1];
  const float* b_attn = (const float*)d_in[2];
  const float* W_proj = (const float*)d_in[3];
  const float* b_proj = (const float*)d_in[4];
  float* out = (float*)d_out;

  char* ws = (char*)d_ws;
  size_t off = 0;
  auto alloc = [&](size_t bytes) -> char* {
    char* p = ws + off;
    off += (bytes + 255) & ~(size_t)255;
    return p;
  };
  unsigned short* xb  = (unsigned short*)alloc((size_t)MM * CC * 2);   // reused as yb
  unsigned short* WaT = (unsigned short*)alloc((size_t)NQKV * CC * 2);
  unsigned short* WpT = (unsigned short*)alloc((size_t)CC * CC * 2);
  unsigned short* qh  = (unsigned short*)alloc((size_t)MM * CC * 2);
  unsigned short* kh  = (unsigned short*)alloc((size_t)MM * CC * 2);
  unsigned short* vh  = (unsigned short*)alloc((size_t)MM * CC * 2);
  float* KV   = (float*)alloc((size_t)BB * HH * NCH * DD * DD * 4);
  float* Ksum = (float*)alloc((size_t)BB * HH * NCH * DD * 4);
  unsigned short* yb = xb;  // xb dead after gemm_qkv

  cvt_x_kernel<<<(MM * CC) / 1024, 256, 0, stream>>>(x, xb, MM * CC);
  transpose_cvt_kernel<<<dim3(NQKV / 32, CC / 32), dim3(32, 8), 0, stream>>>(W_attn, WaT, CC, NQKV);
  transpose_cvt_kernel<<<dim3(CC / 32, CC / 32), dim3(32, 8), 0, stream>>>(W_proj, WpT, CC, CC);
  gemm_qkv_kernel<<<dim3(NQKV / 128, MM / 128), 256, 0, stream>>>(xb, WaT, b_attn, qh, kh, vh);
  chunk_state_kernel<<<BB * HH * NCH, 256, 0, stream>>>(kh, vh, KV, Ksum);
  prefix_state_kernel<<<BB * HH, 256, 0, stream>>>(KV, Ksum);
  chunk_attn_kernel<<<BB * HH * NCH, 256, 0, stream>>>(qh, kh, vh, KV, Ksum, yb);
  gemm_proj_kernel<<<dim3(CC / 128, MM / 128), 256, 0, stream>>>(yb, WpT, b_proj, out);
}

// Round 2
// 285.136 us; speedup vs baseline: 1.5480x; 1.5480x over previous
//
#include <hip/hip_runtime.h>
#include <math.h>

// Problem constants (reference: B=4, T=2048, C=1024, H=16, d=64)
#define BB   4
#define TT   2048
#define CC   1024
#define HH   16
#define DD   64
#define MM   (BB*TT)     // 8192 rows
#define NQKV (3*CC)      // 3072
#define LCH  128         // attention chunk length
#define NCH  (TT/LCH)    // 16 chunks per (b,h)
#define EPSF 1e-6f

// LDS strides (in shorts) — padded to break bank aliasing (row stride !≡ 0 mod 128B)
#define QKST 72          // Q/K tile row stride
#define PST  136         // P tile row stride
#define VTST 136         // V-transposed tile row stride

typedef __bf16 bf16x8 __attribute__((ext_vector_type(8)));
typedef float  floatx4 __attribute__((ext_vector_type(4)));

__device__ __forceinline__ unsigned short f2bf(float f) {
  union { float f; unsigned int u; } v; v.f = f;
  unsigned int r = v.u + 0x7fffu + ((v.u >> 16) & 1u); // RNE
  return (unsigned short)(r >> 16);
}
__device__ __forceinline__ float bf2f(unsigned short s) {
  union { unsigned int u; float f; } v; v.u = ((unsigned int)s) << 16;
  return v.f;
}
__device__ __forceinline__ float featmap(float v) {
  // elu(v)+1
  return v > 0.f ? v + 1.f : __expf(v);
}

// ---------------- conversion kernels ----------------

__global__ __launch_bounds__(256) void cvt_x_kernel(const float* __restrict__ x,
                                                    unsigned short* __restrict__ xb, int n) {
  int i = (blockIdx.x * 256 + threadIdx.x) * 4;
  if (i < n) {
    float4 f = *(const float4*)(x + i);
    ushort4 o;
    o.x = f2bf(f.x); o.y = f2bf(f.y); o.z = f2bf(f.z); o.w = f2bf(f.w);
    *(ushort4*)(xb + i) = o;
  }
}

// W: R x Cc fp32 row-major  ->  out: Cc x R bf16 row-major (transposed)
__global__ __launch_bounds__(256) void transpose_cvt_kernel(const float* __restrict__ W,
                                                            unsigned short* __restrict__ out,
                                                            int R, int Cc) {
  __shared__ float tile[32][33];
  int bx = blockIdx.x * 32;   // source col base
  int by = blockIdx.y * 32;   // source row base
  int tx = threadIdx.x, ty = threadIdx.y;  // 32 x 8
  #pragma unroll
  for (int i = ty; i < 32; i += 8)
    tile[i][tx] = W[(size_t)(by + i) * Cc + bx + tx];
  __syncthreads();
  #pragma unroll
  for (int i = ty; i < 32; i += 8)
    out[(size_t)(bx + i) * R + by + tx] = f2bf(tile[tx][i]);
}

// ---------------- GEMM 1: qkv = x @ W_attn + b, split + feature map ----------------
__global__ __launch_bounds__(256) void gemm_qkv_kernel(
    const unsigned short* __restrict__ A, const unsigned short* __restrict__ Bt,
    const float* __restrict__ bias,
    unsigned short* __restrict__ qh, unsigned short* __restrict__ kh,
    unsigned short* __restrict__ vh) {
  const int K = CC;
  __shared__ __align__(16) unsigned short As[128 * 32];
  __shared__ __align__(16) unsigned short Bs[128 * 32];
  int tid = threadIdx.x;
  int wave = tid >> 6, lane = tid & 63;
  int lr = lane & 15, lq = lane >> 4;
  int m0 = blockIdx.y * 128, n0 = blockIdx.x * 128;
  int wm = (wave >> 1) * 64, wn = (wave & 1) * 64;
  floatx4 acc[4][4] = {};
  for (int k0 = 0; k0 < K; k0 += 32) {
    #pragma unroll
    for (int s = tid; s < 512; s += 256) {
      int row = s >> 2, k8 = (s & 3) << 3;
      *(uint4*)&As[row * 32 + k8] = *(const uint4*)&A[(size_t)(m0 + row) * K + k0 + k8];
      *(uint4*)&Bs[row * 32 + k8] = *(const uint4*)&Bt[(size_t)(n0 + row) * K + k0 + k8];
    }
    __syncthreads();
    bf16x8 af[4], bfr[4];
    #pragma unroll
    for (int i = 0; i < 4; i++) af[i] = *(const bf16x8*)&As[(wm + i * 16 + lr) * 32 + lq * 8];
    #pragma unroll
    for (int j = 0; j < 4; j++) bfr[j] = *(const bf16x8*)&Bs[(wn + j * 16 + lr) * 32 + lq * 8];
    #pragma unroll
    for (int i = 0; i < 4; i++)
      #pragma unroll
      for (int j = 0; j < 4; j++)
        acc[i][j] = __builtin_amdgcn_mfma_f32_16x16x32_bf16(af[i], bfr[j], acc[i][j], 0, 0, 0);
    __syncthreads();
  }
  // epilogue: C/D layout col=lane&15, row=(lane>>4)*4+reg
  #pragma unroll
  for (int i = 0; i < 4; i++) {
    #pragma unroll
    for (int j = 0; j < 4; j++) {
      #pragma unroll
      for (int r = 0; r < 4; r++) {
        int row = wm + i * 16 + lq * 4 + r;
        int col = wn + j * 16 + lr;
        int m = m0 + row, n = n0 + col;
        float v = acc[i][j][r] + bias[n];
        int which = n >> 10, c = n & 1023;
        int h = c >> 6, dd = c & 63;
        int b = m >> 11, t = m & 2047;
        size_t idx = (((size_t)(b * HH + h)) * TT + t) * DD + dd;
        if (which == 0)      qh[idx] = f2bf(featmap(v));
        else if (which == 1) kh[idx] = f2bf(featmap(v));
        else                 vh[idx] = f2bf(v);
      }
    }
  }
}

// ---------------- Phase A: per-chunk KV state ----------------
// grid: B*H*NCH blocks, 256 threads. KV[blk] = K_c^T V_c (d x d fp32), Ksum[blk]
__global__ __launch_bounds__(256) void chunk_state_kernel(
    const unsigned short* __restrict__ kh, const unsigned short* __restrict__ vh,
    float* __restrict__ KV, float* __restrict__ Ksum) {
  int blk = blockIdx.x;
  int bh = blk / NCH, c = blk % NCH;
  const unsigned short* kp = kh + ((size_t)bh * TT + c * LCH) * DD;
  const unsigned short* vp = vh + ((size_t)bh * TT + c * LCH) * DD;
  __shared__ float ks[LCH * DD];  // 32 KB
  __shared__ float vs[LCH * DD];  // 32 KB
  for (int e = threadIdx.x; e < LCH * DD; e += 256) {
    ks[e] = bf2f(kp[e]);
    vs[e] = bf2f(vp[e]);
  }
  __syncthreads();
  int j = threadIdx.x & 63, i0 = (threadIdx.x >> 6) * 16;
  float acc[16];
  #pragma unroll
  for (int ii = 0; ii < 16; ii++) acc[ii] = 0.f;
  for (int t = 0; t < LCH; t++) {
    float vv = vs[t * DD + j];
    #pragma unroll
    for (int ii = 0; ii < 16; ii++) acc[ii] += ks[t * DD + i0 + ii] * vv;
  }
  float* kvout = KV + (size_t)blk * DD * DD;
  #pragma unroll
  for (int ii = 0; ii < 16; ii++) kvout[(i0 + ii) * DD + j] = acc[ii];
  if (threadIdx.x < DD) {
    int i = threadIdx.x;
    float s = 0.f;
    for (int t = 0; t < LCH; t++) s += ks[t * DD + i];
    Ksum[(size_t)blk * DD + i] = s;
  }
}

// ---------------- Phase B: exclusive prefix over chunks -> bf16 transposed SP_ext ---
// SPb[blk] is 80x64 bf16: rows 0..63 = SP_prefix^T (SPb[j][i] = sum_{c'<c} KV[c'][i][j]),
// row 64 = ksum_prefix, rows 65..79 = 0. Laid out so mfma B-frags load contiguously.
// grid: B*H blocks, 256 threads
__global__ __launch_bounds__(256) void prefix_state_kernel(const float* __restrict__ KV,
                                                           const float* __restrict__ Ksum,
                                                           unsigned short* __restrict__ SPb) {
  int bh = blockIdx.x;
  int tid = threadIdx.x;
  int i = tid >> 2;            // SP row (k-index), 0..63
  int j0 = (tid & 3) * 16;     // SP col base
  float run[16];
  #pragma unroll
  for (int ii = 0; ii < 16; ii++) run[ii] = 0.f;
  float krun = 0.f;
  for (int c = 0; c < NCH; c++) {
    size_t base = ((size_t)bh * NCH + c) * (80 * 64);
    const float* kv = KV + ((size_t)bh * NCH + c) * (DD * DD) + (size_t)i * DD + j0;
    #pragma unroll
    for (int jj = 0; jj < 16; jj++) {
      SPb[base + (size_t)(j0 + jj) * 64 + i] = f2bf(run[jj]);  // transposed write
      run[jj] += kv[jj];
    }
    if (tid < DD) {
      SPb[base + 64 * 64 + tid] = f2bf(krun);
      krun += Ksum[((size_t)bh * NCH + c) * DD + tid];
    }
    for (int e = tid; e < 15 * 64; e += 256)
      SPb[base + 65 * 64 + e] = 0;
  }
}

// ---------------- Phase C: per-chunk attention output (MFMA) ----------------
// One block per (b,h,chunk): 4 waves, wave w owns rows [w*32, w*32+32).
//   acc[i][jt] (jt=0..4, 80 cols): cols 0..63 numerator, col 64 denominator.
//   acc += Q @ SP_ext  (inter-chunk, B-frags straight from global SPb)
//   S    = Q @ K^T     -> causal mask -> bf16 P via LDS (C-layout -> A-layout)
//   acc += P @ V_ext   (V_ext: V^T with ones row at j=64)
__global__ __launch_bounds__(256) void chunk_attn_kernel(
    const unsigned short* __restrict__ qh, const unsigned short* __restrict__ kh,
    const unsigned short* __restrict__ vh, const unsigned short* __restrict__ SPb,
    unsigned short* __restrict__ yb) {
  // region A: Qs[128][72] + Ks[128][72] = 18432 shorts, reused as P[128][136] = 17408
  // region B: Vt[80][136] = 10880 shorts
  __shared__ __align__(16) unsigned short lds[128 * QKST * 2 + 80 * VTST];  // 58624 B
  unsigned short* Qs = lds;                       // [128][QKST]
  unsigned short* Ks = lds + 128 * QKST;          // [128][QKST]
  unsigned short* P  = lds;                       // [128][PST] (after Qs/Ks dead)
  unsigned short* Vt = lds + 128 * QKST * 2;      // [80][VTST]

  int blk = blockIdx.x;
  int bh = blk / NCH, c = blk % NCH;
  int b = bh / HH, h = bh % HH;
  int tid = threadIdx.x;
  const unsigned short* qp = qh + ((size_t)bh * TT + c * LCH) * DD;
  const unsigned short* kp = kh + ((size_t)bh * TT + c * LCH) * DD;
  const unsigned short* vp = vh + ((size_t)bh * TT + c * LCH) * DD;

  // stage Q, K (row-major, padded stride)
  for (int e = tid; e < 1024; e += 256) {
    int row = e >> 3, k8 = (e & 7) * 8;
    *(uint4*)&Qs[row * QKST + k8] = *(const uint4*)&qp[(size_t)row * DD + k8];
    *(uint4*)&Ks[row * QKST + k8] = *(const uint4*)&kp[(size_t)row * DD + k8];
  }
  // stage V transposed: Vt[j][t] = V[t][j]; lane-major in t so writes spread banks
  {
    int t = tid & 127;
    for (int j8 = (tid >> 7) * 8; j8 < DD; j8 += 16) {
      union { uint4 u; unsigned short s[8]; } w;
      w.u = *(const uint4*)&vp[(size_t)t * DD + j8];
      #pragma unroll
      for (int jj = 0; jj < 8; jj++) Vt[(j8 + jj) * VTST + t] = w.s[jj];
    }
  }
  // ones row (j=64) and zero rows (65..79)
  for (int e = tid; e < 16 * 128; e += 256) {
    int rr = e >> 7, n = e & 127;
    Vt[(64 + rr) * VTST + n] = (rr == 0) ? (unsigned short)0x3F80 : (unsigned short)0;
  }
  __syncthreads();

  int wave = tid >> 6, lane = tid & 63;
  int lr = lane & 15, lq = lane >> 4;
  int mbase = wave * 32;

  // Q A-frags for this wave's two 16-row tiles
  bf16x8 aq[2][2];
  #pragma unroll
  for (int i = 0; i < 2; i++)
    #pragma unroll
    for (int kk = 0; kk < 2; kk++)
      aq[i][kk] = *(const bf16x8*)&Qs[(mbase + i * 16 + lr) * QKST + kk * 32 + lq * 8];

  floatx4 acc[2][5] = {};
  // inter-chunk: acc += Q @ SP_ext (B-frags from global)
  const unsigned short* spb = SPb + (size_t)blk * (80 * 64);
  #pragma unroll
  for (int jt = 0; jt < 5; jt++)
    #pragma unroll
    for (int kk = 0; kk < 2; kk++) {
      bf16x8 bsp = *(const bf16x8*)&spb[(jt * 16 + lr) * 64 + kk * 32 + lq * 8];
      acc[0][jt] = __builtin_amdgcn_mfma_f32_16x16x32_bf16(aq[0][kk], bsp, acc[0][jt], 0, 0, 0);
      acc[1][jt] = __builtin_amdgcn_mfma_f32_16x16x32_bf16(aq[1][kk], bsp, acc[1][jt], 0, 0, 0);
    }
  // intra-chunk scores: S = Q @ K^T
  floatx4 sacc[2][8] = {};
  #pragma unroll
  for (int nt = 0; nt < 8; nt++)
    #pragma unroll
    for (int kk = 0; kk < 2; kk++) {
      bf16x8 bk = *(const bf16x8*)&Ks[(nt * 16 + lr) * QKST + kk * 32 + lq * 8];
      sacc[0][nt] = __builtin_amdgcn_mfma_f32_16x16x32_bf16(aq[0][kk], bk, sacc[0][nt], 0, 0, 0);
      sacc[1][nt] = __builtin_amdgcn_mfma_f32_16x16x32_bf16(aq[1][kk], bk, sacc[1][nt], 0, 0, 0);
    }
  __syncthreads();  // everyone done reading Qs/Ks before P overwrites them

  // causal mask + bf16 round, C-layout -> LDS (A-layout for the PV matmul)
  #pragma unroll
  for (int i = 0; i < 2; i++)
    #pragma unroll
    for (int nt = 0; nt < 8; nt++) {
      int col = nt * 16 + lr;
      #pragma unroll
      for (int r = 0; r < 4; r++) {
        int m = mbase + i * 16 + lq * 4 + r;
        float v = (col <= m) ? sacc[i][nt][r] : 0.f;
        P[m * PST + col] = f2bf(v);
      }
    }
  __syncthreads();

  // acc += P @ V_ext
  #pragma unroll
  for (int kk4 = 0; kk4 < 4; kk4++) {
    bf16x8 ap0 = *(const bf16x8*)&P[(mbase + lr) * PST + kk4 * 32 + lq * 8];
    bf16x8 ap1 = *(const bf16x8*)&P[(mbase + 16 + lr) * PST + kk4 * 32 + lq * 8];
    #pragma unroll
    for (int jt = 0; jt < 5; jt++) {
      bf16x8 bv = *(const bf16x8*)&Vt[(jt * 16 + lr) * VTST + kk4 * 32 + lq * 8];
      acc[0][jt] = __builtin_amdgcn_mfma_f32_16x16x32_bf16(ap0, bv, acc[0][jt], 0, 0, 0);
      acc[1][jt] = __builtin_amdgcn_mfma_f32_16x16x32_bf16(ap1, bv, acc[1][jt], 0, 0, 0);
    }
  }

  // epilogue: den lives in col 64 -> lane (lq,0); broadcast within the 16-lane group
  int srclane = lq << 4;
  #pragma unroll
  for (int i = 0; i < 2; i++) {
    #pragma unroll
    for (int r = 0; r < 4; r++) {
      float den = __shfl(acc[i][4][r], srclane, 64);
      float inv = 1.f / (den + EPSF);
      int tg = c * LCH + mbase + i * 16 + lq * 4 + r;
      size_t base = ((size_t)b * TT + tg) * CC + h * DD;
      #pragma unroll
      for (int jt = 0; jt < 4; jt++)
        yb[base + jt * 16 + lr] = f2bf(acc[i][jt][r] * inv);
    }
  }
}

// ---------------- GEMM 2: out = y @ W_proj + b_proj (fp32 out) ----------------
__global__ __launch_bounds__(256) void gemm_proj_kernel(
    const unsigned short* __restrict__ A, const unsigned short* __restrict__ Bt,
    const float* __restrict__ bias, float* __restrict__ out) {
  const int K = CC;
  __shared__ __align__(16) unsigned short As[128 * 32];
  __shared__ __align__(16) unsigned short Bs[128 * 32];
  int tid = threadIdx.x;
  int wave = tid >> 6, lane = tid & 63;
  int lr = lane & 15, lq = lane >> 4;
  int m0 = blockIdx.y * 128, n0 = blockIdx.x * 128;
  int wm = (wave >> 1) * 64, wn = (wave & 1) * 64;
  floatx4 acc[4][4] = {};
  for (int k0 = 0; k0 < K; k0 += 32) {
    #pragma unroll
    for (int s = tid; s < 512; s += 256) {
      int row = s >> 2, k8 = (s & 3) << 3;
      *(uint4*)&As[row * 32 + k8] = *(const uint4*)&A[(size_t)(m0 + row) * K + k0 + k8];
      *(uint4*)&Bs[row * 32 + k8] = *(const uint4*)&Bt[(size_t)(n0 + row) * K + k0 + k8];
    }
    __syncthreads();
    bf16x8 af[4], bfr[4];
    #pragma unroll
    for (int i = 0; i < 4; i++) af[i] = *(const bf16x8*)&As[(wm + i * 16 + lr) * 32 + lq * 8];
    #pragma unroll
    for (int j = 0; j < 4; j++) bfr[j] = *(const bf16x8*)&Bs[(wn + j * 16 + lr) * 32 + lq * 8];
    #pragma unroll
    for (int i = 0; i < 4; i++)
      #pragma unroll
      for (int j = 0; j < 4; j++)
        acc[i][j] = __builtin_amdgcn_mfma_f32_16x16x32_bf16(af[i], bfr[j], acc[i][j], 0, 0, 0);
    __syncthreads();
  }
  #pragma unroll
  for (int i = 0; i < 4; i++) {
    #pragma unroll
    for (int j = 0; j < 4; j++) {
      #pragma unroll
      for (int r = 0; r < 4; r++) {
        int row = wm + i * 16 + lq * 4 + r;
        int col = wn + j * 16 + lr;
        int m = m0 + row, n = n0 + col;
        out[(size_t)m * CC + n] = acc[i][j][r] + bias[n];
      }
    }
  }
}

// ---------------- host launch ----------------
extern "C" void kernel_launch(void* const* d_in, const int* in_sizes, int n_in,
                              void* d_out, int out_size, void* d_ws, size_t ws_size,
                              hipStream_t stream) {
  const float* x      = (const float*)d_in[0];
  const float* W_attn = (const float*)d_in[1];
  const float* b_attn = (const float*)d_in[2];
  const float* W_proj = (const float*)d_in[3];
  const float* b_proj = (const float*)d_in[4];
  float* out = (float*)d_out;

  char* ws = (char*)d_ws;
  size_t off = 0;
  auto alloc = [&](size_t bytes) -> char* {
    char* p = ws + off;
    off += (bytes + 255) & ~(size_t)255;
    return p;
  };
  unsigned short* xb  = (unsigned short*)alloc((size_t)MM * CC * 2);   // reused as yb
  unsigned short* WaT = (unsigned short*)alloc((size_t)NQKV * CC * 2);
  unsigned short* WpT = (unsigned short*)alloc((size_t)CC * CC * 2);
  unsigned short* qh  = (unsigned short*)alloc((size_t)MM * CC * 2);
  unsigned short* kh  = (unsigned short*)alloc((size_t)MM * CC * 2);
  unsigned short* vh  = (unsigned short*)alloc((size_t)MM * CC * 2);
  float* KV   = (float*)alloc((size_t)BB * HH * NCH * DD * DD * 4);
  float* Ksum = (float*)alloc((size_t)BB * HH * NCH * DD * 4);
  unsigned short* SPb = (unsigned short*)alloc((size_t)BB * HH * NCH * 80 * 64 * 2);
  unsigned short* yb = xb;  // xb dead after gemm_qkv

  cvt_x_kernel<<<(MM * CC) / 1024, 256, 0, stream>>>(x, xb, MM * CC);
  transpose_cvt_kernel<<<dim3(NQKV / 32, CC / 32), dim3(32, 8), 0, stream>>>(W_attn, WaT, CC, NQKV);
  transpose_cvt_kernel<<<dim3(CC / 32, CC / 32), dim3(32, 8), 0, stream>>>(W_proj, WpT, CC, CC);
  gemm_qkv_kernel<<<dim3(NQKV / 128, MM / 128), 256, 0, stream>>>(xb, WaT, b_attn, qh, kh, vh);
  chunk_state_kernel<<<BB * HH * NCH, 256, 0, stream>>>(kh, vh, KV, Ksum);
  prefix_state_kernel<<<BB * HH, 256, 0, stream>>>(KV, Ksum, SPb);
  chunk_attn_kernel<<<BB * HH * NCH, 256, 0, stream>>>(qh, kh, vh, SPb, yb);
  gemm_proj_kernel<<<dim3(CC / 128, MM / 128), 256, 0, stream>>>(yb, WpT, b_proj, out);
}

// Round 3
// 264.660 us; speedup vs baseline: 1.6678x; 1.0774x over previous
//
#include <hip/hip_runtime.h>
#include <math.h>

// Problem constants (reference: B=4, T=2048, C=1024, H=16, d=64)
#define BB   4
#define TT   2048
#define CC   1024
#define HH   16
#define DD   64
#define MM   (BB*TT)     // 8192 rows
#define NQKV (3*CC)      // 3072
#define LCH  128         // attention chunk length
#define NCH  (TT/LCH)    // 16 chunks per (b,h)
#define EPSF 1e-6f

// LDS strides (in shorts) for chunk_attn — padded to break bank aliasing
#define QKST 72          // Q/K tile row stride
#define PST  136         // P tile row stride
#define VTST 136         // V-transposed tile row stride

typedef __bf16 bf16x8 __attribute__((ext_vector_type(8)));
typedef float  floatx4 __attribute__((ext_vector_type(4)));

__device__ __forceinline__ unsigned short f2bf(float f) {
  union { float f; unsigned int u; } v; v.f = f;
  unsigned int r = v.u + 0x7fffu + ((v.u >> 16) & 1u); // RNE
  return (unsigned short)(r >> 16);
}
__device__ __forceinline__ float bf2f(unsigned short s) {
  union { unsigned int u; float f; } v; v.u = ((unsigned int)s) << 16;
  return v.f;
}
__device__ __forceinline__ float featmap(float v) {
  // elu(v)+1
  return v > 0.f ? v + 1.f : __expf(v);
}
// async global->LDS, 16B per lane; LDS dest = wave-uniform base + lane*16
__device__ __forceinline__ void gld_lds_b128(const unsigned short* g, unsigned short* l) {
  __builtin_amdgcn_global_load_lds(
      (const __attribute__((address_space(1))) unsigned int*)g,
      (__attribute__((address_space(3))) unsigned int*)l, 16, 0, 0);
}

// ---------------- conversion kernels ----------------

__global__ __launch_bounds__(256) void cvt_x_kernel(const float* __restrict__ x,
                                                    unsigned short* __restrict__ xb, int n) {
  int i = (blockIdx.x * 256 + threadIdx.x) * 4;
  if (i < n) {
    float4 f = *(const float4*)(x + i);
    ushort4 o;
    o.x = f2bf(f.x); o.y = f2bf(f.y); o.z = f2bf(f.z); o.w = f2bf(f.w);
    *(ushort4*)(xb + i) = o;
  }
}

// W: R x Cc fp32 row-major  ->  out: Cc x R bf16 row-major (transposed)
__global__ __launch_bounds__(256) void transpose_cvt_kernel(const float* __restrict__ W,
                                                            unsigned short* __restrict__ out,
                                                            int R, int Cc) {
  __shared__ float tile[32][33];
  int bx = blockIdx.x * 32;   // source col base
  int by = blockIdx.y * 32;   // source row base
  int tx = threadIdx.x, ty = threadIdx.y;  // 32 x 8
  #pragma unroll
  for (int i = ty; i < 32; i += 8)
    tile[i][tx] = W[(size_t)(by + i) * Cc + bx + tx];
  __syncthreads();
  #pragma unroll
  for (int i = ty; i < 32; i += 8)
    out[(size_t)(bx + i) * R + by + tx] = f2bf(tile[tx][i]);
}

// ======================= m97-style MFMA GEMM core =========================
// A: M x K bf16 row-major, Bt: N x K bf16 row-major. 128x128 tile, BK=32.
// 256 threads = 4 waves; wave w computes 64x64 quadrant (wm=(w>>1)*64, wn=(w&1)*64).
// Staging: global_load_lds width=16; LDS image is [128][32] shorts with the
// 8-short k-chunk XOR-swizzled by (row&3) to cut frag-read bank conflicts 8->4 way.
// acc layout: C/D col=lane&15, row=(lane>>4)*4+reg.
#define GEMM_K_LOOP(A_, Bt_, K_)                                                 \
  __shared__ __align__(16) unsigned short As[128 * 32];                          \
  __shared__ __align__(16) unsigned short Bs[128 * 32];                          \
  int tid = threadIdx.x;                                                         \
  int wave = tid >> 6, lane = tid & 63;                                          \
  int lr = lane & 15, lq = lane >> 4;                                            \
  int m0 = blockIdx.y * 128, n0 = blockIdx.x * 128;                              \
  int wm = (wave >> 1) * 64, wn = (wave & 1) * 64;                               \
  int lrow = lane >> 2;                 /* 0..15: row within 16-row chunk */     \
  int lk = (lane & 3) ^ (lrow & 3);     /* swizzled source k-chunk */            \
  int ci0 = wave * 2;                                                            \
  const unsigned short* gA0 = A_ + (size_t)(m0 + ci0 * 16 + lrow) * K_ + lk * 8; \
  const unsigned short* gA1 = gA0 + 16 * K_;                                     \
  const unsigned short* gB0 = Bt_ + (size_t)(n0 + ci0 * 16 + lrow) * K_ + lk * 8;\
  const unsigned short* gB1 = gB0 + 16 * K_;                                     \
  unsigned short* lA0 = As + ci0 * 512;                                          \
  unsigned short* lB0 = Bs + ci0 * 512;                                          \
  floatx4 acc[4][4] = {};                                                        \
  for (int k0 = 0; k0 < K_; k0 += 32) {                                          \
    __syncthreads(); /* prior frag reads done before overwrite */                \
    gld_lds_b128(gA0 + k0, lA0);                                                 \
    gld_lds_b128(gA1 + k0, lA0 + 512);                                           \
    gld_lds_b128(gB0 + k0, lB0);                                                 \
    gld_lds_b128(gB1 + k0, lB0 + 512);                                           \
    __syncthreads(); /* staged data visible */                                   \
    bf16x8 af[4], bfr[4];                                                        \
    _Pragma("unroll")                                                            \
    for (int i = 0; i < 4; i++)                                                  \
      af[i] = *(const bf16x8*)&As[(wm + i * 16 + lr) * 32 + ((lq ^ (lr & 3)) << 3)]; \
    _Pragma("unroll")                                                            \
    for (int j = 0; j < 4; j++)                                                  \
      bfr[j] = *(const bf16x8*)&Bs[(wn + j * 16 + lr) * 32 + ((lq ^ (lr & 3)) << 3)]; \
    _Pragma("unroll")                                                            \
    for (int i = 0; i < 4; i++)                                                  \
      _Pragma("unroll")                                                          \
      for (int j = 0; j < 4; j++)                                                \
        acc[i][j] = __builtin_amdgcn_mfma_f32_16x16x32_bf16(af[i], bfr[j], acc[i][j], 0, 0, 0); \
  }

// ---------------- GEMM 1: qkv = x @ W_attn + b, split + feature map ----------------
__global__ __launch_bounds__(256) void gemm_qkv_kernel(
    const unsigned short* __restrict__ A, const unsigned short* __restrict__ Bt,
    const float* __restrict__ bias,
    unsigned short* __restrict__ qh, unsigned short* __restrict__ kh,
    unsigned short* __restrict__ vh) {
  GEMM_K_LOOP(A, Bt, CC)
  // epilogue: C/D layout col=lane&15, row=(lane>>4)*4+reg
  #pragma unroll
  for (int i = 0; i < 4; i++) {
    #pragma unroll
    for (int j = 0; j < 4; j++) {
      #pragma unroll
      for (int r = 0; r < 4; r++) {
        int row = wm + i * 16 + lq * 4 + r;
        int col = wn + j * 16 + lr;
        int m = m0 + row, n = n0 + col;
        float v = acc[i][j][r] + bias[n];
        int which = n >> 10, c = n & 1023;
        int h = c >> 6, dd = c & 63;
        int b = m >> 11, t = m & 2047;
        size_t idx = (((size_t)(b * HH + h)) * TT + t) * DD + dd;
        if (which == 0)      qh[idx] = f2bf(featmap(v));
        else if (which == 1) kh[idx] = f2bf(featmap(v));
        else                 vh[idx] = f2bf(v);
      }
    }
  }
}

// ---------------- GEMM 2: out = y @ W_proj + b_proj (fp32 out) ----------------
__global__ __launch_bounds__(256) void gemm_proj_kernel(
    const unsigned short* __restrict__ A, const unsigned short* __restrict__ Bt,
    const float* __restrict__ bias, float* __restrict__ out) {
  GEMM_K_LOOP(A, Bt, CC)
  #pragma unroll
  for (int i = 0; i < 4; i++) {
    #pragma unroll
    for (int j = 0; j < 4; j++) {
      #pragma unroll
      for (int r = 0; r < 4; r++) {
        int row = wm + i * 16 + lq * 4 + r;
        int col = wn + j * 16 + lr;
        int m = m0 + row, n = n0 + col;
        out[(size_t)m * CC + n] = acc[i][j][r] + bias[n];
      }
    }
  }
}

// ---------------- Phase A: per-chunk KV state ----------------
// grid: B*H*NCH blocks, 256 threads. KV[blk] = K_c^T V_c (d x d fp32), Ksum[blk]
__global__ __launch_bounds__(256) void chunk_state_kernel(
    const unsigned short* __restrict__ kh, const unsigned short* __restrict__ vh,
    float* __restrict__ KV, float* __restrict__ Ksum) {
  int blk = blockIdx.x;
  int bh = blk / NCH, c = blk % NCH;
  const unsigned short* kp = kh + ((size_t)bh * TT + c * LCH) * DD;
  const unsigned short* vp = vh + ((size_t)bh * TT + c * LCH) * DD;
  __shared__ float ks[LCH * DD];  // 32 KB
  __shared__ float vs[LCH * DD];  // 32 KB
  for (int e = threadIdx.x; e < LCH * DD; e += 256) {
    ks[e] = bf2f(kp[e]);
    vs[e] = bf2f(vp[e]);
  }
  __syncthreads();
  int j = threadIdx.x & 63, i0 = (threadIdx.x >> 6) * 16;
  float acc[16];
  #pragma unroll
  for (int ii = 0; ii < 16; ii++) acc[ii] = 0.f;
  for (int t = 0; t < LCH; t++) {
    float vv = vs[t * DD + j];
    #pragma unroll
    for (int ii = 0; ii < 16; ii++) acc[ii] += ks[t * DD + i0 + ii] * vv;
  }
  float* kvout = KV + (size_t)blk * DD * DD;
  #pragma unroll
  for (int ii = 0; ii < 16; ii++) kvout[(i0 + ii) * DD + j] = acc[ii];
  if (threadIdx.x < DD) {
    int i = threadIdx.x;
    float s = 0.f;
    for (int t = 0; t < LCH; t++) s += ks[t * DD + i];
    Ksum[(size_t)blk * DD + i] = s;
  }
}

// ---------------- Phase B: exclusive prefix over chunks -> bf16 transposed SP_ext ---
// SPb[blk] is 80x64 bf16: rows 0..63 = SP_prefix^T, row 64 = ksum_prefix, 65..79 = 0.
// grid: B*H blocks, 256 threads
__global__ __launch_bounds__(256) void prefix_state_kernel(const float* __restrict__ KV,
                                                           const float* __restrict__ Ksum,
                                                           unsigned short* __restrict__ SPb) {
  int bh = blockIdx.x;
  int tid = threadIdx.x;
  int i = tid >> 2;            // SP row (k-index), 0..63
  int j0 = (tid & 3) * 16;     // SP col base
  float run[16];
  #pragma unroll
  for (int ii = 0; ii < 16; ii++) run[ii] = 0.f;
  float krun = 0.f;
  for (int c = 0; c < NCH; c++) {
    size_t base = ((size_t)bh * NCH + c) * (80 * 64);
    const float* kv = KV + ((size_t)bh * NCH + c) * (DD * DD) + (size_t)i * DD + j0;
    #pragma unroll
    for (int jj = 0; jj < 16; jj++) {
      SPb[base + (size_t)(j0 + jj) * 64 + i] = f2bf(run[jj]);  // transposed write
      run[jj] += kv[jj];
    }
    if (tid < DD) {
      SPb[base + 64 * 64 + tid] = f2bf(krun);
      krun += Ksum[((size_t)bh * NCH + c) * DD + tid];
    }
    for (int e = tid; e < 15 * 64; e += 256)
      SPb[base + 65 * 64 + e] = 0;
  }
}

// ---------------- Phase C: per-chunk attention output (MFMA) ----------------
__global__ __launch_bounds__(256) void chunk_attn_kernel(
    const unsigned short* __restrict__ qh, const unsigned short* __restrict__ kh,
    const unsigned short* __restrict__ vh, const unsigned short* __restrict__ SPb,
    unsigned short* __restrict__ yb) {
  // region A: Qs[128][72] + Ks[128][72] = 18432 shorts, reused as P[128][136] = 17408
  // region B: Vt[80][136] = 10880 shorts
  __shared__ __align__(16) unsigned short lds[128 * QKST * 2 + 80 * VTST];  // 58624 B
  unsigned short* Qs = lds;                       // [128][QKST]
  unsigned short* Ks = lds + 128 * QKST;          // [128][QKST]
  unsigned short* P  = lds;                       // [128][PST] (after Qs/Ks dead)
  unsigned short* Vt = lds + 128 * QKST * 2;      // [80][VTST]

  int blk = blockIdx.x;
  int bh = blk / NCH, c = blk % NCH;
  int b = bh / HH, h = bh % HH;
  int tid = threadIdx.x;
  const unsigned short* qp = qh + ((size_t)bh * TT + c * LCH) * DD;
  const unsigned short* kp = kh + ((size_t)bh * TT + c * LCH) * DD;
  const unsigned short* vp = vh + ((size_t)bh * TT + c * LCH) * DD;

  // stage Q, K (row-major, padded stride)
  for (int e = tid; e < 1024; e += 256) {
    int row = e >> 3, k8 = (e & 7) * 8;
    *(uint4*)&Qs[row * QKST + k8] = *(const uint4*)&qp[(size_t)row * DD + k8];
    *(uint4*)&Ks[row * QKST + k8] = *(const uint4*)&kp[(size_t)row * DD + k8];
  }
  // stage V transposed: Vt[j][t] = V[t][j]
  {
    int t = tid & 127;
    for (int j8 = (tid >> 7) * 8; j8 < DD; j8 += 16) {
      union { uint4 u; unsigned short s[8]; } w;
      w.u = *(const uint4*)&vp[(size_t)t * DD + j8];
      #pragma unroll
      for (int jj = 0; jj < 8; jj++) Vt[(j8 + jj) * VTST + t] = w.s[jj];
    }
  }
  // ones row (j=64) and zero rows (65..79)
  for (int e = tid; e < 16 * 128; e += 256) {
    int rr = e >> 7, n = e & 127;
    Vt[(64 + rr) * VTST + n] = (rr == 0) ? (unsigned short)0x3F80 : (unsigned short)0;
  }
  __syncthreads();

  int wave = tid >> 6, lane = tid & 63;
  int lr = lane & 15, lq = lane >> 4;
  int mbase = wave * 32;

  // Q A-frags for this wave's two 16-row tiles
  bf16x8 aq[2][2];
  #pragma unroll
  for (int i = 0; i < 2; i++)
    #pragma unroll
    for (int kk = 0; kk < 2; kk++)
      aq[i][kk] = *(const bf16x8*)&Qs[(mbase + i * 16 + lr) * QKST + kk * 32 + lq * 8];

  floatx4 acc[2][5] = {};
  // inter-chunk: acc += Q @ SP_ext (B-frags from global)
  const unsigned short* spb = SPb + (size_t)blk * (80 * 64);
  #pragma unroll
  for (int jt = 0; jt < 5; jt++)
    #pragma unroll
    for (int kk = 0; kk < 2; kk++) {
      bf16x8 bsp = *(const bf16x8*)&spb[(jt * 16 + lr) * 64 + kk * 32 + lq * 8];
      acc[0][jt] = __builtin_amdgcn_mfma_f32_16x16x32_bf16(aq[0][kk], bsp, acc[0][jt], 0, 0, 0);
      acc[1][jt] = __builtin_amdgcn_mfma_f32_16x16x32_bf16(aq[1][kk], bsp, acc[1][jt], 0, 0, 0);
    }
  // intra-chunk scores: S = Q @ K^T
  floatx4 sacc[2][8] = {};
  #pragma unroll
  for (int nt = 0; nt < 8; nt++)
    #pragma unroll
    for (int kk = 0; kk < 2; kk++) {
      bf16x8 bk = *(const bf16x8*)&Ks[(nt * 16 + lr) * QKST + kk * 32 + lq * 8];
      sacc[0][nt] = __builtin_amdgcn_mfma_f32_16x16x32_bf16(aq[0][kk], bk, sacc[0][nt], 0, 0, 0);
      sacc[1][nt] = __builtin_amdgcn_mfma_f32_16x16x32_bf16(aq[1][kk], bk, sacc[1][nt], 0, 0, 0);
    }
  __syncthreads();  // everyone done reading Qs/Ks before P overwrites them

  // causal mask + bf16 round, C-layout -> LDS (A-layout for the PV matmul)
  #pragma unroll
  for (int i = 0; i < 2; i++)
    #pragma unroll
    for (int nt = 0; nt < 8; nt++) {
      int col = nt * 16 + lr;
      #pragma unroll
      for (int r = 0; r < 4; r++) {
        int m = mbase + i * 16 + lq * 4 + r;
        float v = (col <= m) ? sacc[i][nt][r] : 0.f;
        P[m * PST + col] = f2bf(v);
      }
    }
  __syncthreads();

  // acc += P @ V_ext
  #pragma unroll
  for (int kk4 = 0; kk4 < 4; kk4++) {
    bf16x8 ap0 = *(const bf16x8*)&P[(mbase + lr) * PST + kk4 * 32 + lq * 8];
    bf16x8 ap1 = *(const bf16x8*)&P[(mbase + 16 + lr) * PST + kk4 * 32 + lq * 8];
    #pragma unroll
    for (int jt = 0; jt < 5; jt++) {
      bf16x8 bv = *(const bf16x8*)&Vt[(jt * 16 + lr) * VTST + kk4 * 32 + lq * 8];
      acc[0][jt] = __builtin_amdgcn_mfma_f32_16x16x32_bf16(ap0, bv, acc[0][jt], 0, 0, 0);
      acc[1][jt] = __builtin_amdgcn_mfma_f32_16x16x32_bf16(ap1, bv, acc[1][jt], 0, 0, 0);
    }
  }

  // epilogue: den lives in col 64 -> lane (lq,0); broadcast within the 16-lane group
  int srclane = lq << 4;
  #pragma unroll
  for (int i = 0; i < 2; i++) {
    #pragma unroll
    for (int r = 0; r < 4; r++) {
      float den = __shfl(acc[i][4][r], srclane, 64);
      float inv = 1.f / (den + EPSF);
      int tg = c * LCH + mbase + i * 16 + lq * 4 + r;
      size_t base = ((size_t)b * TT + tg) * CC + h * DD;
      #pragma unroll
      for (int jt = 0; jt < 4; jt++)
        yb[base + jt * 16 + lr] = f2bf(acc[i][jt][r] * inv);
    }
  }
}

// ---------------- host launch ----------------
extern "C" void kernel_launch(void* const* d_in, const int* in_sizes, int n_in,
                              void* d_out, int out_size, void* d_ws, size_t ws_size,
                              hipStream_t stream) {
  const float* x      = (const float*)d_in[0];
  const float* W_attn = (const float*)d_in[1];
  const float* b_attn = (const float*)d_in[2];
  const float* W_proj = (const float*)d_in[3];
  const float* b_proj = (const float*)d_in[4];
  float* out = (float*)d_out;

  char* ws = (char*)d_ws;
  size_t off = 0;
  auto alloc = [&](size_t bytes) -> char* {
    char* p = ws + off;
    off += (bytes + 255) & ~(size_t)255;
    return p;
  };
  unsigned short* xb  = (unsigned short*)alloc((size_t)MM * CC * 2);   // reused as yb
  unsigned short* WaT = (unsigned short*)alloc((size_t)NQKV * CC * 2);
  unsigned short* WpT = (unsigned short*)alloc((size_t)CC * CC * 2);
  unsigned short* qh  = (unsigned short*)alloc((size_t)MM * CC * 2);
  unsigned short* kh  = (unsigned short*)alloc((size_t)MM * CC * 2);
  unsigned short* vh  = (unsigned short*)alloc((size_t)MM * CC * 2);
  float* KV   = (float*)alloc((size_t)BB * HH * NCH * DD * DD * 4);
  float* Ksum = (float*)alloc((size_t)BB * HH * NCH * DD * 4);
  unsigned short* SPb = (unsigned short*)alloc((size_t)BB * HH * NCH * 80 * 64 * 2);
  unsigned short* yb = xb;  // xb dead after gemm_qkv

  cvt_x_kernel<<<(MM * CC) / 1024, 256, 0, stream>>>(x, xb, MM * CC);
  transpose_cvt_kernel<<<dim3(NQKV / 32, CC / 32), dim3(32, 8), 0, stream>>>(W_attn, WaT, CC, NQKV);
  transpose_cvt_kernel<<<dim3(CC / 32, CC / 32), dim3(32, 8), 0, stream>>>(W_proj, WpT, CC, CC);
  gemm_qkv_kernel<<<dim3(NQKV / 128, MM / 128), 256, 0, stream>>>(xb, WaT, b_attn, qh, kh, vh);
  chunk_state_kernel<<<BB * HH * NCH, 256, 0, stream>>>(kh, vh, KV, Ksum);
  prefix_state_kernel<<<BB * HH, 256, 0, stream>>>(KV, Ksum, SPb);
  chunk_attn_kernel<<<BB * HH * NCH, 256, 0, stream>>>(qh, kh, vh, SPb, yb);
  gemm_proj_kernel<<<dim3(CC / 128, MM / 128), 256, 0, stream>>>(yb, WpT, b_proj, out);
}

// Round 4
// 244.605 us; speedup vs baseline: 1.8046x; 1.0820x over previous
//
#include <hip/hip_runtime.h>
#include <math.h>

// Problem constants (reference: B=4, T=2048, C=1024, H=16, d=64)
#define BB   4
#define TT   2048
#define CC   1024
#define HH   16
#define DD   64
#define MM   (BB*TT)     // 8192 rows
#define NQKV (3*CC)      // 3072
#define LCH  128         // attention chunk length
#define NCH  (TT/LCH)    // 16 chunks per (b,h)
#define EPSF 1e-6f

// LDS strides (in shorts) for attention kernels — padded to break bank aliasing
#define QKST 72          // Q/K tile row stride
#define PST  136         // P tile row stride
#define VTST 136         // V-transposed tile row stride

typedef __bf16 bf16x8 __attribute__((ext_vector_type(8)));
typedef float  floatx4 __attribute__((ext_vector_type(4)));

__device__ __forceinline__ unsigned short f2bf(float f) {
  union { float f; unsigned int u; } v; v.f = f;
  unsigned int r = v.u + 0x7fffu + ((v.u >> 16) & 1u); // RNE
  return (unsigned short)(r >> 16);
}
__device__ __forceinline__ float bf2f(unsigned short s) {
  union { unsigned int u; float f; } v; v.u = ((unsigned int)s) << 16;
  return v.f;
}
__device__ __forceinline__ float featmap(float v) {
  // elu(v)+1
  return v > 0.f ? v + 1.f : __expf(v);
}
// async global->LDS, 16B per lane; LDS dest = wave-uniform base + lane*16
__device__ __forceinline__ void gld_lds_b128(const unsigned short* g, unsigned short* l) {
  __builtin_amdgcn_global_load_lds(
      (const __attribute__((address_space(1))) unsigned int*)g,
      (__attribute__((address_space(3))) unsigned int*)l, 16, 0, 0);
}

// ---------------- conversion kernels ----------------

__global__ __launch_bounds__(256) void cvt_x_kernel(const float* __restrict__ x,
                                                    unsigned short* __restrict__ xb, int n) {
  int i = (blockIdx.x * 256 + threadIdx.x) * 4;
  if (i < n) {
    float4 f = *(const float4*)(x + i);
    ushort4 o;
    o.x = f2bf(f.x); o.y = f2bf(f.y); o.z = f2bf(f.z); o.w = f2bf(f.w);
    *(ushort4*)(xb + i) = o;
  }
}

// W: R x Cc fp32 row-major  ->  out: Cc x R bf16 row-major (transposed)
__global__ __launch_bounds__(256) void transpose_cvt_kernel(const float* __restrict__ W,
                                                            unsigned short* __restrict__ out,
                                                            int R, int Cc) {
  __shared__ float tile[32][33];
  int bx = blockIdx.x * 32;   // source col base
  int by = blockIdx.y * 32;   // source row base
  int tx = threadIdx.x, ty = threadIdx.y;  // 32 x 8
  #pragma unroll
  for (int i = ty; i < 32; i += 8)
    tile[i][tx] = W[(size_t)(by + i) * Cc + bx + tx];
  __syncthreads();
  #pragma unroll
  for (int i = ty; i < 32; i += 8)
    out[(size_t)(bx + i) * R + by + tx] = f2bf(tile[tx][i]);
}

// ======================= m97-style MFMA GEMM core (BK=64) =========================
// A: M x K bf16 row-major, Bt: N x K bf16 row-major. 128x128 tile, BK=64.
// 256 threads = 4 waves; wave w computes 64x64 quadrant (wm=(w>>1)*64, wn=(w&1)*64).
// Staging: global_load_lds width=16; LDS image [128][64] shorts, 8-short k-chunks
// XOR-swizzled by (row&7). 32 MFMA per barrier pair (2x the BK=32 version).
// acc layout: C/D col=lane&15, row=(lane>>4)*4+reg.
#define GEMM_K_LOOP(A_, Bt_, K_)                                                 \
  __shared__ __align__(16) unsigned short As[128 * 64];                          \
  __shared__ __align__(16) unsigned short Bs[128 * 64];                          \
  int tid = threadIdx.x;                                                         \
  int wave = tid >> 6, lane = tid & 63;                                          \
  int lr = lane & 15, lq = lane >> 4;                                            \
  int m0 = blockIdx.y * 128, n0 = blockIdx.x * 128;                              \
  int wm = (wave >> 1) * 64, wn = (wave & 1) * 64;                               \
  int lrow = lane >> 3;                 /* 0..7: row within 8-row chunk */       \
  int lk = (lane & 7) ^ lrow;           /* swizzled source k-chunk */            \
  int rbase = wave * 32;                                                         \
  const unsigned short* gA = A_ + (size_t)(m0 + rbase + lrow) * K_ + lk * 8;     \
  const unsigned short* gB = Bt_ + (size_t)(n0 + rbase + lrow) * K_ + lk * 8;    \
  unsigned short* lA = As + rbase * 64;                                          \
  unsigned short* lB = Bs + rbase * 64;                                          \
  floatx4 acc[4][4] = {};                                                        \
  for (int k0 = 0; k0 < K_; k0 += 64) {                                          \
    __syncthreads(); /* prior frag reads done before overwrite */                \
    _Pragma("unroll")                                                            \
    for (int g = 0; g < 4; g++) {                                                \
      gld_lds_b128(gA + k0 + (size_t)g * 8 * K_, lA + g * 512);                  \
      gld_lds_b128(gB + k0 + (size_t)g * 8 * K_, lB + g * 512);                  \
    }                                                                            \
    __syncthreads(); /* staged data visible */                                   \
    _Pragma("unroll")                                                            \
    for (int kk = 0; kk < 2; kk++) {                                             \
      bf16x8 af[4], bfr[4];                                                      \
      _Pragma("unroll")                                                          \
      for (int i = 0; i < 4; i++)                                                \
        af[i] = *(const bf16x8*)&As[(wm + i * 16 + lr) * 64 + ((((kk << 2) + lq) ^ (lr & 7)) << 3)]; \
      _Pragma("unroll")                                                          \
      for (int j = 0; j < 4; j++)                                                \
        bfr[j] = *(const bf16x8*)&Bs[(wn + j * 16 + lr) * 64 + ((((kk << 2) + lq) ^ (lr & 7)) << 3)]; \
      _Pragma("unroll")                                                          \
      for (int i = 0; i < 4; i++)                                                \
        _Pragma("unroll")                                                        \
        for (int j = 0; j < 4; j++)                                              \
          acc[i][j] = __builtin_amdgcn_mfma_f32_16x16x32_bf16(af[i], bfr[j], acc[i][j], 0, 0, 0); \
    }                                                                            \
  }

// ---------------- GEMM 1: qkv = x @ W_attn + b, split + feature map ----------------
__global__ __launch_bounds__(256) void gemm_qkv_kernel(
    const unsigned short* __restrict__ A, const unsigned short* __restrict__ Bt,
    const float* __restrict__ bias,
    unsigned short* __restrict__ qh, unsigned short* __restrict__ kh,
    unsigned short* __restrict__ vh) {
  GEMM_K_LOOP(A, Bt, CC)
  // epilogue: C/D layout col=lane&15, row=(lane>>4)*4+reg
  #pragma unroll
  for (int i = 0; i < 4; i++) {
    #pragma unroll
    for (int j = 0; j < 4; j++) {
      #pragma unroll
      for (int r = 0; r < 4; r++) {
        int row = wm + i * 16 + lq * 4 + r;
        int col = wn + j * 16 + lr;
        int m = m0 + row, n = n0 + col;
        float v = acc[i][j][r] + bias[n];
        int which = n >> 10, c = n & 1023;
        int h = c >> 6, dd = c & 63;
        int b = m >> 11, t = m & 2047;
        size_t idx = (((size_t)(b * HH + h)) * TT + t) * DD + dd;
        if (which == 0)      qh[idx] = f2bf(featmap(v));
        else if (which == 1) kh[idx] = f2bf(featmap(v));
        else                 vh[idx] = f2bf(v);
      }
    }
  }
}

// ---------------- GEMM 2: out = y @ W_proj + b_proj (fp32 out) ----------------
__global__ __launch_bounds__(256) void gemm_proj_kernel(
    const unsigned short* __restrict__ A, const unsigned short* __restrict__ Bt,
    const float* __restrict__ bias, float* __restrict__ out) {
  GEMM_K_LOOP(A, Bt, CC)
  #pragma unroll
  for (int i = 0; i < 4; i++) {
    #pragma unroll
    for (int j = 0; j < 4; j++) {
      #pragma unroll
      for (int r = 0; r < 4; r++) {
        int row = wm + i * 16 + lq * 4 + r;
        int col = wn + j * 16 + lr;
        int m = m0 + row, n = n0 + col;
        out[(size_t)m * CC + n] = acc[i][j][r] + bias[n];
      }
    }
  }
}

// ---------------- Phase A: per-chunk KV state (MFMA) ----------------
// grid: B*H*NCH blocks, 256 threads.
// KVx[blk][80][64] fp32, stored TRANSPOSED: KVx[j][i] = (K_c^T V_ext)[i][j],
// where V_ext = [V | ones | 0...] so col 64 is ksum. Rows 65..79 are zero.
__global__ __launch_bounds__(256) void chunk_state_kernel(
    const unsigned short* __restrict__ kh, const unsigned short* __restrict__ vh,
    float* __restrict__ KVx) {
  __shared__ __align__(16) unsigned short Kt[64 * VTST];   // K^T: Kt[i][t]
  __shared__ __align__(16) unsigned short Vt[80 * VTST];   // V^T + ones/zero rows
  int blk = blockIdx.x;
  int bh = blk / NCH, c = blk % NCH;
  int tid = threadIdx.x;
  const unsigned short* kp = kh + ((size_t)bh * TT + c * LCH) * DD;
  const unsigned short* vp = vh + ((size_t)bh * TT + c * LCH) * DD;
  {
    int t = tid & 127;
    for (int j8 = (tid >> 7) * 8; j8 < DD; j8 += 16) {
      union { uint4 u; unsigned short s[8]; } wk, wv;
      wk.u = *(const uint4*)&kp[(size_t)t * DD + j8];
      wv.u = *(const uint4*)&vp[(size_t)t * DD + j8];
      #pragma unroll
      for (int jj = 0; jj < 8; jj++) {
        Kt[(j8 + jj) * VTST + t] = wk.s[jj];
        Vt[(j8 + jj) * VTST + t] = wv.s[jj];
      }
    }
  }
  for (int e = tid; e < 16 * 128; e += 256) {
    int rr = e >> 7, n = e & 127;
    Vt[(64 + rr) * VTST + n] = (rr == 0) ? (unsigned short)0x3F80 : (unsigned short)0;
  }
  __syncthreads();
  int wave = tid >> 6, lane = tid & 63;
  int lr = lane & 15, lq = lane >> 4;
  int i0 = wave * 16;             // wave's 16-row band of K^T (i dimension)
  floatx4 acc[5] = {};
  #pragma unroll
  for (int kk = 0; kk < 4; kk++) {
    bf16x8 a = *(const bf16x8*)&Kt[(i0 + lr) * VTST + kk * 32 + lq * 8];
    #pragma unroll
    for (int jt = 0; jt < 5; jt++) {
      bf16x8 b = *(const bf16x8*)&Vt[(jt * 16 + lr) * VTST + kk * 32 + lq * 8];
      acc[jt] = __builtin_amdgcn_mfma_f32_16x16x32_bf16(a, b, acc[jt], 0, 0, 0);
    }
  }
  // C/D: col(j) = lane&15, row(i) = i0 + lq*4 + r; store transposed [j][i]
  float* o = KVx + (size_t)blk * 5120;
  #pragma unroll
  for (int jt = 0; jt < 5; jt++)
    #pragma unroll
    for (int r = 0; r < 4; r++)
      o[(jt * 16 + lr) * 64 + i0 + lq * 4 + r] = acc[jt][r];
}

// ---------------- Phase B: exclusive prefix over chunks -> bf16 SP_ext ----------
// SPb[blk][80][64] bf16 = sum_{c'<c} KVx[bh][c'][.][.]  (same [j][i] layout).
// grid: B*H*5 blocks (one per (bh, 16-row j-band)), 256 threads, 4 elems each.
__global__ __launch_bounds__(256) void prefix_state_kernel(const float* __restrict__ KVx,
                                                           unsigned short* __restrict__ SPb) {
  int bh = blockIdx.x / 5, jb = blockIdx.x % 5;
  int e = jb * 1024 + threadIdx.x * 4;
  float run0 = 0.f, run1 = 0.f, run2 = 0.f, run3 = 0.f;
  for (int c = 0; c < NCH; c++) {
    size_t base = ((size_t)bh * NCH + c) * 5120 + e;
    float4 v = *(const float4*)&KVx[base];
    ushort4 o;
    o.x = f2bf(run0); o.y = f2bf(run1); o.z = f2bf(run2); o.w = f2bf(run3);
    *(ushort4*)&SPb[base] = o;
    run0 += v.x; run1 += v.y; run2 += v.z; run3 += v.w;
  }
}

// ---------------- Phase C: per-chunk attention output (MFMA) ----------------
__global__ __launch_bounds__(256) void chunk_attn_kernel(
    const unsigned short* __restrict__ qh, const unsigned short* __restrict__ kh,
    const unsigned short* __restrict__ vh, const unsigned short* __restrict__ SPb,
    unsigned short* __restrict__ yb) {
  // region A: Qs[128][72] + Ks[128][72] = 18432 shorts, reused as P[128][136] = 17408
  // region B: Vt[80][136] = 10880 shorts
  __shared__ __align__(16) unsigned short lds[128 * QKST * 2 + 80 * VTST];  // 58624 B
  unsigned short* Qs = lds;                       // [128][QKST]
  unsigned short* Ks = lds + 128 * QKST;          // [128][QKST]
  unsigned short* P  = lds;                       // [128][PST] (after Qs/Ks dead)
  unsigned short* Vt = lds + 128 * QKST * 2;      // [80][VTST]

  int blk = blockIdx.x;
  int bh = blk / NCH, c = blk % NCH;
  int b = bh / HH, h = bh % HH;
  int tid = threadIdx.x;
  const unsigned short* qp = qh + ((size_t)bh * TT + c * LCH) * DD;
  const unsigned short* kp = kh + ((size_t)bh * TT + c * LCH) * DD;
  const unsigned short* vp = vh + ((size_t)bh * TT + c * LCH) * DD;

  // stage Q, K (row-major, padded stride)
  for (int e = tid; e < 1024; e += 256) {
    int row = e >> 3, k8 = (e & 7) * 8;
    *(uint4*)&Qs[row * QKST + k8] = *(const uint4*)&qp[(size_t)row * DD + k8];
    *(uint4*)&Ks[row * QKST + k8] = *(const uint4*)&kp[(size_t)row * DD + k8];
  }
  // stage V transposed: Vt[j][t] = V[t][j]
  {
    int t = tid & 127;
    for (int j8 = (tid >> 7) * 8; j8 < DD; j8 += 16) {
      union { uint4 u; unsigned short s[8]; } w;
      w.u = *(const uint4*)&vp[(size_t)t * DD + j8];
      #pragma unroll
      for (int jj = 0; jj < 8; jj++) Vt[(j8 + jj) * VTST + t] = w.s[jj];
    }
  }
  // ones row (j=64) and zero rows (65..79)
  for (int e = tid; e < 16 * 128; e += 256) {
    int rr = e >> 7, n = e & 127;
    Vt[(64 + rr) * VTST + n] = (rr == 0) ? (unsigned short)0x3F80 : (unsigned short)0;
  }
  __syncthreads();

  int wave = tid >> 6, lane = tid & 63;
  int lr = lane & 15, lq = lane >> 4;
  int mbase = wave * 32;

  // Q A-frags for this wave's two 16-row tiles
  bf16x8 aq[2][2];
  #pragma unroll
  for (int i = 0; i < 2; i++)
    #pragma unroll
    for (int kk = 0; kk < 2; kk++)
      aq[i][kk] = *(const bf16x8*)&Qs[(mbase + i * 16 + lr) * QKST + kk * 32 + lq * 8];

  floatx4 acc[2][5] = {};
  // inter-chunk: acc += Q @ SP_ext (B-frags from global)
  const unsigned short* spb = SPb + (size_t)blk * (80 * 64);
  #pragma unroll
  for (int jt = 0; jt < 5; jt++)
    #pragma unroll
    for (int kk = 0; kk < 2; kk++) {
      bf16x8 bsp = *(const bf16x8*)&spb[(jt * 16 + lr) * 64 + kk * 32 + lq * 8];
      acc[0][jt] = __builtin_amdgcn_mfma_f32_16x16x32_bf16(aq[0][kk], bsp, acc[0][jt], 0, 0, 0);
      acc[1][jt] = __builtin_amdgcn_mfma_f32_16x16x32_bf16(aq[1][kk], bsp, acc[1][jt], 0, 0, 0);
    }
  // intra-chunk scores: S = Q @ K^T
  floatx4 sacc[2][8] = {};
  #pragma unroll
  for (int nt = 0; nt < 8; nt++)
    #pragma unroll
    for (int kk = 0; kk < 2; kk++) {
      bf16x8 bk = *(const bf16x8*)&Ks[(nt * 16 + lr) * QKST + kk * 32 + lq * 8];
      sacc[0][nt] = __builtin_amdgcn_mfma_f32_16x16x32_bf16(aq[0][kk], bk, sacc[0][nt], 0, 0, 0);
      sacc[1][nt] = __builtin_amdgcn_mfma_f32_16x16x32_bf16(aq[1][kk], bk, sacc[1][nt], 0, 0, 0);
    }
  __syncthreads();  // everyone done reading Qs/Ks before P overwrites them

  // causal mask + bf16 round, C-layout -> LDS (A-layout for the PV matmul)
  #pragma unroll
  for (int i = 0; i < 2; i++)
    #pragma unroll
    for (int nt = 0; nt < 8; nt++) {
      int col = nt * 16 + lr;
      #pragma unroll
      for (int r = 0; r < 4; r++) {
        int m = mbase + i * 16 + lq * 4 + r;
        float v = (col <= m) ? sacc[i][nt][r] : 0.f;
        P[m * PST + col] = f2bf(v);
      }
    }
  __syncthreads();

  // acc += P @ V_ext
  #pragma unroll
  for (int kk4 = 0; kk4 < 4; kk4++) {
    bf16x8 ap0 = *(const bf16x8*)&P[(mbase + lr) * PST + kk4 * 32 + lq * 8];
    bf16x8 ap1 = *(const bf16x8*)&P[(mbase + 16 + lr) * PST + kk4 * 32 + lq * 8];
    #pragma unroll
    for (int jt = 0; jt < 5; jt++) {
      bf16x8 bv = *(const bf16x8*)&Vt[(jt * 16 + lr) * VTST + kk4 * 32 + lq * 8];
      acc[0][jt] = __builtin_amdgcn_mfma_f32_16x16x32_bf16(ap0, bv, acc[0][jt], 0, 0, 0);
      acc[1][jt] = __builtin_amdgcn_mfma_f32_16x16x32_bf16(ap1, bv, acc[1][jt], 0, 0, 0);
    }
  }

  // epilogue: den lives in col 64 -> lane (lq,0); broadcast within the 16-lane group
  int srclane = lq << 4;
  #pragma unroll
  for (int i = 0; i < 2; i++) {
    #pragma unroll
    for (int r = 0; r < 4; r++) {
      float den = __shfl(acc[i][4][r], srclane, 64);
      float inv = 1.f / (den + EPSF);
      int tg = c * LCH + mbase + i * 16 + lq * 4 + r;
      size_t base = ((size_t)b * TT + tg) * CC + h * DD;
      #pragma unroll
      for (int jt = 0; jt < 4; jt++)
        yb[base + jt * 16 + lr] = f2bf(acc[i][jt][r] * inv);
    }
  }
}

// ---------------- host launch ----------------
extern "C" void kernel_launch(void* const* d_in, const int* in_sizes, int n_in,
                              void* d_out, int out_size, void* d_ws, size_t ws_size,
                              hipStream_t stream) {
  const float* x      = (const float*)d_in[0];
  const float* W_attn = (const float*)d_in[1];
  const float* b_attn = (const float*)d_in[2];
  const float* W_proj = (const float*)d_in[3];
  const float* b_proj = (const float*)d_in[4];
  float* out = (float*)d_out;

  char* ws = (char*)d_ws;
  size_t off = 0;
  auto alloc = [&](size_t bytes) -> char* {
    char* p = ws + off;
    off += (bytes + 255) & ~(size_t)255;
    return p;
  };
  unsigned short* xb  = (unsigned short*)alloc((size_t)MM * CC * 2);   // reused as yb
  unsigned short* WaT = (unsigned short*)alloc((size_t)NQKV * CC * 2);
  unsigned short* WpT = (unsigned short*)alloc((size_t)CC * CC * 2);
  unsigned short* qh  = (unsigned short*)alloc((size_t)MM * CC * 2);
  unsigned short* kh  = (unsigned short*)alloc((size_t)MM * CC * 2);
  unsigned short* vh  = (unsigned short*)alloc((size_t)MM * CC * 2);
  float* KVx = (float*)alloc((size_t)BB * HH * NCH * 80 * 64 * 4);
  unsigned short* SPb = (unsigned short*)alloc((size_t)BB * HH * NCH * 80 * 64 * 2);
  unsigned short* yb = xb;  // xb dead after gemm_qkv

  cvt_x_kernel<<<(MM * CC) / 1024, 256, 0, stream>>>(x, xb, MM * CC);
  transpose_cvt_kernel<<<dim3(NQKV / 32, CC / 32), dim3(32, 8), 0, stream>>>(W_attn, WaT, CC, NQKV);
  transpose_cvt_kernel<<<dim3(CC / 32, CC / 32), dim3(32, 8), 0, stream>>>(W_proj, WpT, CC, CC);
  gemm_qkv_kernel<<<dim3(NQKV / 128, MM / 128), 256, 0, stream>>>(xb, WaT, b_attn, qh, kh, vh);
  chunk_state_kernel<<<BB * HH * NCH, 256, 0, stream>>>(kh, vh, KVx);
  prefix_state_kernel<<<BB * HH * 5, 256, 0, stream>>>(KVx, SPb);
  chunk_attn_kernel<<<BB * HH * NCH, 256, 0, stream>>>(qh, kh, vh, SPb, yb);
  gemm_proj_kernel<<<dim3(CC / 128, MM / 128), 256, 0, stream>>>(yb, WpT, b_proj, out);
}